// Round 1
// baseline (346.733 us; speedup 1.0000x reference)
//
#include <hip/hip_runtime.h>

typedef _Float16 h16;
typedef _Float16 h16x8 __attribute__((ext_vector_type(8)));
typedef _Float16 h16x4 __attribute__((ext_vector_type(4)));
typedef float f32x4 __attribute__((ext_vector_type(4)));

#define DEV static __device__ __forceinline__

// ---- workspace layout (h16 element offsets) ----
static constexpr size_t OFF_DATA = 0;          // 16384*256        data (f16)
static constexpr size_t OFF_W0T  = 4194304;    // 512*256          mlp_w0^T
static constexpr size_t OFF_W1T  = 4325376;    // 512*512          mlp_w1^T
static constexpr size_t OFF_W2PD = 4587520;    // 512*768          [mlp_w2 ; 2*pd_w]^T
static constexpr size_t OFF_QKVT = 4980736;    // 1536*512         [q|k|v]^T
static constexpr size_t OFF_OPIT = 5767168;    // 512*768          [o_w ; pi_w]^T
static constexpr size_t OFF_X1   = 6160384;    // 16384*512  X1 / KV-lo / PRE2
static constexpr size_t OFF_X2   = 14548992;   // 16384*512  X2 / KV-hi
static constexpr size_t OFF_KV   = OFF_X1;     // 16384*1024 (k|v per node)
static constexpr size_t OFF_P    = 22937600;   // 16384*512  P / LOCAL(in-place) / ATTN
// total: 31,326,208 elems = ~60 MB

DEV void gload16(const void* g, void* l)
{
    __builtin_amdgcn_global_load_lds(
        (__attribute__((address_space(1))) void*)(void*)g,
        (__attribute__((address_space(3))) void*)l, 16, 0, 0);
}

DEV float eluf(float x) { return x > 0.f ? x : __expf(x) - 1.f; }

// ---- data fp32 -> f16 ----
__global__ __launch_bounds__(256)
void k_cvt_data(const float* __restrict__ src, h16* __restrict__ dst)
{
    size_t i = ((size_t)blockIdx.x * 256 + threadIdx.x) * 4;
    float4 v = *(const float4*)(src + i);
    h16x4 o;
    o[0] = (h16)v.x; o[1] = (h16)v.y; o[2] = (h16)v.z; o[3] = (h16)v.w;
    *(h16x4*)(dst + i) = o;
}

// ---- all weight transposes (src [K][512] fp32 -> dst [n][k] f16, optional scale) ----
__global__ void k_prep_w(const float* __restrict__ w0, const float* __restrict__ w1,
                         const float* __restrict__ w2, const float* __restrict__ pdw,
                         const float* __restrict__ qw, const float* __restrict__ kw,
                         const float* __restrict__ vw, const float* __restrict__ ow,
                         const float* __restrict__ piw, h16* __restrict__ ws)
{
    int b = blockIdx.x;
    const float* src; h16* dst; int K, dstStride, dstKOff = 0, tb; float scale = 1.f;
    const int N = 512;
    if (b < 128)       { src = w0;  dst = ws + OFF_W0T;           K = 256; dstStride = 256; tb = 0; }
    else if (b < 384)  { src = w1;  dst = ws + OFF_W1T;           K = 512; dstStride = 512; tb = 128; }
    else if (b < 640)  { src = w2;  dst = ws + OFF_W2PD;          K = 512; dstStride = 768; tb = 384; }
    else if (b < 768)  { src = pdw; dst = ws + OFF_W2PD;          K = 256; dstStride = 768; dstKOff = 512; scale = 2.f; tb = 640; }
    else if (b < 1024) { src = qw;  dst = ws + OFF_QKVT;          K = 512; dstStride = 512; tb = 768; }
    else if (b < 1280) { src = kw;  dst = ws + OFF_QKVT + 262144; K = 512; dstStride = 512; tb = 1024; }
    else if (b < 1536) { src = vw;  dst = ws + OFF_QKVT + 524288; K = 512; dstStride = 512; tb = 1280; }
    else if (b < 1792) { src = ow;  dst = ws + OFF_OPIT;          K = 512; dstStride = 768; tb = 1536; }
    else               { src = piw; dst = ws + OFF_OPIT;          K = 256; dstStride = 768; dstKOff = 512; tb = 1792; }
    int t = b - tb;
    int tilesK = K >> 5;
    int tk = t % tilesK, tn = t / tilesK;
    __shared__ float tile[32][33];
    int tx = threadIdx.x, ty = threadIdx.y;
    #pragma unroll
    for (int r = 0; r < 32; r += 8)
        tile[ty + r][tx] = src[(size_t)(tk * 32 + ty + r) * N + tn * 32 + tx] * scale;
    __syncthreads();
    #pragma unroll
    for (int r = 0; r < 32; r += 8) {
        int n = tn * 32 + ty + r, k = tk * 32 + tx;
        dst[(size_t)n * dstStride + dstKOff + k] = (h16)tile[tx][ty + r];
    }
}

// ---- GEMM: C[M,N] = concat(A1[K1],A2[K2]) @ BT^T + bias, m97-style 128x128 tile ----
// BIASMODE: 0 = bias1[col]; 1 = bias1[col] + b2scale*bias2[col];
//           2 = segmented qkv bias + split output (out: cols 0..511 stride 512,
//               out2: cols 512..1535 stride 1024)
template<int BIASMODE, bool DOELU>
__global__ __launch_bounds__(256)
void k_gemm(const h16* __restrict__ A1, const h16* __restrict__ A2,
            const int K1, const int K2,
            const h16* __restrict__ BT,
            const float* __restrict__ bias1, const float* __restrict__ bias2,
            const float* __restrict__ bias3, const float b2scale,
            h16* __restrict__ out, h16* __restrict__ out2, const int N)
{
    const int Kt = K1 + K2;
    __shared__ __align__(16) h16 sA[128 * 32];
    __shared__ __align__(16) h16 sB[128 * 32];
    const int tid  = threadIdx.x;
    const int lane = tid & 63;
    const int mBase = blockIdx.y * 128, nBase = blockIdx.x * 128;
    const int wm = ((tid >> 7) & 1) * 64;
    const int wn = ((tid >> 6) & 1) * 64;
    const f32x4 zero = {0.f, 0.f, 0.f, 0.f};
    f32x4 acc[4][4];
    #pragma unroll
    for (int i = 0; i < 4; ++i) {
        #pragma unroll
        for (int j = 0; j < 4; ++j) acc[i][j] = zero;
    }

    const int ldR = tid >> 2;          // 0..63
    const int ldC = (tid & 3) * 8;     // k element offset
    const int lm = lane & 15, lk = (lane >> 4) * 8;

    for (int k0 = 0; k0 < Kt; k0 += 32) {
        const h16* Ab; int Ak, As;
        if (k0 < K1) { Ab = A1; Ak = k0;      As = K1; }
        else         { Ab = A2; Ak = k0 - K1; As = K2; }
        #pragma unroll
        for (int r = 0; r < 2; ++r) {
            const int row = r * 64 + ldR;
            gload16(Ab + (size_t)(mBase + row) * As + Ak + ldC, &sA[row * 32 + ldC]);
            gload16(BT + (size_t)(nBase + row) * Kt + k0 + ldC, &sB[row * 32 + ldC]);
        }
        __syncthreads();
        h16x8 af[4], bfr[4];
        #pragma unroll
        for (int i = 0; i < 4; ++i) af[i]  = *(const h16x8*)&sA[(wm + i * 16 + lm) * 32 + lk];
        #pragma unroll
        for (int j = 0; j < 4; ++j) bfr[j] = *(const h16x8*)&sB[(wn + j * 16 + lm) * 32 + lk];
        #pragma unroll
        for (int i = 0; i < 4; ++i) {
            #pragma unroll
            for (int j = 0; j < 4; ++j)
                acc[i][j] = __builtin_amdgcn_mfma_f32_16x16x32_f16(af[i], bfr[j], acc[i][j], 0, 0, 0);
        }
        __syncthreads();
    }

    const int lr4 = (lane >> 4) * 4;
    #pragma unroll
    for (int j = 0; j < 4; ++j) {
        const int col = nBase + wn + j * 16 + lm;
        float bv;
        if (BIASMODE == 0) bv = bias1[col];
        else if (BIASMODE == 1) bv = bias1[col] + b2scale * bias2[col];
        else {
            const int seg = col >> 9;
            const float* bp = seg == 0 ? bias1 : (seg == 1 ? bias2 : bias3);
            bv = bp[col & 511];
        }
        #pragma unroll
        for (int i = 0; i < 4; ++i) {
            const int row0 = mBase + wm + i * 16 + lr4;
            #pragma unroll
            for (int r = 0; r < 4; ++r) {
                float v = acc[i][j][r] + bv;
                if (DOELU) v = eluf(v);
                if (BIASMODE == 2) {
                    if (col < 512) out [(size_t)(row0 + r) * 512  + col]         = (h16)v;
                    else           out2[(size_t)(row0 + r) * 1024 + (col - 512)] = (h16)v;
                } else {
                    out[(size_t)(row0 + r) * N + col] = (h16)v;
                }
            }
        }
    }
}

// ---- layernorm (one wave per 512-row), optional ELU, optional fp32 out ----
template<bool DOELU, bool OUTF32>
__global__ __launch_bounds__(256)
void k_ln(const h16* __restrict__ X, const float* __restrict__ g, const float* __restrict__ b,
          h16* __restrict__ outH, float* __restrict__ outF)
{
    const int row  = blockIdx.x * 4 + (threadIdx.x >> 6);
    const int lane = threadIdx.x & 63;
    const h16x8 xv = *(const h16x8*)(X + (size_t)row * 512 + lane * 8);
    float v[8], s = 0.f, ss = 0.f;
    #pragma unroll
    for (int k = 0; k < 8; ++k) { v[k] = (float)xv[k]; s += v[k]; ss += v[k] * v[k]; }
    #pragma unroll
    for (int m = 1; m < 64; m <<= 1) { s += __shfl_xor(s, m, 64); ss += __shfl_xor(ss, m, 64); }
    const float mean = s * (1.f / 512.f);
    const float var  = ss * (1.f / 512.f) - mean * mean;
    const float rstd = rsqrtf(var + 1e-5f);
    #pragma unroll
    for (int k = 0; k < 8; ++k) {
        const int c = lane * 8 + k;
        float y = (v[k] - mean) * rstd * g[c] + b[c];
        if (DOELU) y = eluf(y);
        if (OUTF32) outF[(size_t)row * 512 + c] = y;
        else        outH[(size_t)row * 512 + c] = (h16)y;
    }
}

// ---- neighbor multi-head attention: one block per node ----
__global__ __launch_bounds__(256)
void k_attn(const h16* __restrict__ Q, const h16* __restrict__ KV,
            const int* __restrict__ nbr, h16* __restrict__ outA)
{
    const int n = blockIdx.x;
    __shared__ __align__(16) h16 sQ[512];
    __shared__ __align__(16) h16 sK[16][520];
    __shared__ __align__(16) h16 sV[16][520];
    __shared__ float sW[8][16];
    __shared__ int sNb[16];
    const int tid = threadIdx.x, lane = tid & 63, wave = tid >> 6;
    if (tid < 16) sNb[tid] = nbr[n * 16 + tid];
    __syncthreads();
    if (wave == 0)
        *(h16x8*)&sQ[lane * 8] = *(const h16x8*)&Q[(size_t)n * 512 + lane * 8];
    #pragma unroll
    for (int r = 0; r < 8; ++r) {
        const int p = wave * 8 + r;            // 0..31 (16 K-rows, 16 V-rows)
        const int arr = p >> 4, j = p & 15;
        const h16x8 val = *(const h16x8*)&KV[(size_t)sNb[j] * 1024 + arr * 512 + lane * 8];
        h16* dstp = arr ? &sV[j][lane * 8] : &sK[j][lane * 8];
        *(h16x8*)dstp = val;
    }
    __syncthreads();
    if (tid < 128) {                           // one (head, neighbor) pair per thread
        const int h = tid >> 4, j = tid & 15;
        const h16x8* qv = (const h16x8*)&sQ[h * 64];
        const h16x8* kv = (const h16x8*)&sK[j][h * 64];
        float s = 0.f;
        #pragma unroll
        for (int c = 0; c < 8; ++c) {
            h16x8 qa = qv[c], ka = kv[c];
            #pragma unroll
            for (int e = 0; e < 8; ++e) s += (float)qa[e] * (float)ka[e];
        }
        s *= 0.125f;                           // 1/sqrt(64)
        float mx = s;
        #pragma unroll
        for (int m = 1; m < 16; m <<= 1) mx = fmaxf(mx, __shfl_xor(mx, m, 64));
        const float e = __expf(s - mx);
        float sum = e;
        #pragma unroll
        for (int m = 1; m < 16; m <<= 1) sum += __shfl_xor(sum, m, 64);
        sW[h][j] = e / sum;
    }
    __syncthreads();
    #pragma unroll
    for (int t = 0; t < 2; ++t) {
        const int o = tid + t * 256;
        const int h = o >> 6, a = o & 63;
        float acc = 0.f;
        #pragma unroll
        for (int j = 0; j < 16; ++j) acc += sW[h][j] * (float)sV[j][h * 64 + a];
        outA[(size_t)n * 512 + o] = (h16)acc;
    }
}

extern "C" void kernel_launch(void* const* d_in, const int* in_sizes, int n_in,
                              void* d_out, int out_size, void* d_ws, size_t ws_size,
                              hipStream_t stream)
{
    const float* data = (const float*)d_in[0];
    const int*   nbr  = (const int*)d_in[1];
    const float* w0   = (const float*)d_in[2];
    const float* b0   = (const float*)d_in[3];
    const float* w1   = (const float*)d_in[4];
    const float* b1   = (const float*)d_in[5];
    const float* w2   = (const float*)d_in[6];
    const float* b2   = (const float*)d_in[7];
    const float* pdw  = (const float*)d_in[8];
    const float* pdb  = (const float*)d_in[9];
    const float* piw  = (const float*)d_in[10];
    const float* pib  = (const float*)d_in[11];
    const float* qw   = (const float*)d_in[12];
    const float* qb   = (const float*)d_in[13];
    const float* kw   = (const float*)d_in[14];
    const float* kb   = (const float*)d_in[15];
    const float* vw   = (const float*)d_in[16];
    const float* vb   = (const float*)d_in[17];
    const float* ow   = (const float*)d_in[18];
    const float* ob   = (const float*)d_in[19];
    const float* ln1g = (const float*)d_in[20];
    const float* ln1b = (const float*)d_in[21];
    const float* ln2g = (const float*)d_in[22];
    const float* ln2b = (const float*)d_in[23];
    h16*   ws  = (h16*)d_ws;
    float* out = (float*)d_out;
    h16*   qbuf = (h16*)d_out;   // Q parks in d_out until the attention kernel

    k_cvt_data<<<4096, 256, 0, stream>>>(data, ws + OFF_DATA);
    k_prep_w<<<1920, dim3(32, 8), 0, stream>>>(w0, w1, w2, pdw, qw, kw, vw, ow, piw, ws);

    dim3 gA(4, 128);   // N=512
    dim3 gQ(12, 128);  // N=1536
    // X1 = elu(data @ W0 + b0)
    k_gemm<0, true ><<<gA, 256, 0, stream>>>(ws + OFF_DATA, nullptr, 256, 0, ws + OFF_W0T,
                                             b0, nullptr, nullptr, 0.f,
                                             ws + OFF_X1, nullptr, 512);
    // X2 = elu(X1 @ W1 + b1)
    k_gemm<0, true ><<<gA, 256, 0, stream>>>(ws + OFF_X1, nullptr, 512, 0, ws + OFF_W1T,
                                             b1, nullptr, nullptr, 0.f,
                                             ws + OFF_X2, nullptr, 512);
    // P = X2 @ W2 + 2*(data @ pd_w) + (b2 + 2*pd_b)
    k_gemm<1, false><<<gA, 256, 0, stream>>>(ws + OFF_X2, ws + OFF_DATA, 512, 256, ws + OFF_W2PD,
                                             b2, pdb, nullptr, 2.f,
                                             ws + OFF_P, nullptr, 512);
    // LOCAL = elu(LN(P))  (in-place)
    k_ln<true, false><<<4096, 256, 0, stream>>>(ws + OFF_P, ln1g, ln1b, ws + OFF_P, nullptr);
    // Q(d_out) | KV(ws) = LOCAL @ [q|k|v] + bias
    k_gemm<2, false><<<gQ, 256, 0, stream>>>(ws + OFF_P, nullptr, 512, 0, ws + OFF_QKVT,
                                             qb, kb, vb, 0.f,
                                             qbuf, ws + OFF_KV, 1536);
    // ATTN (-> P region)
    k_attn<<<16384, 256, 0, stream>>>(qbuf, ws + OFF_KV, nbr, ws + OFF_P);
    // PRE2 = ATTN @ o_w + data @ pi_w + (o_b + pi_b)   (-> X1 region)
    k_gemm<1, false><<<gA, 256, 0, stream>>>(ws + OFF_P, ws + OFF_DATA, 512, 256, ws + OFF_OPIT,
                                             ob, pib, nullptr, 1.f,
                                             ws + OFF_X1, nullptr, 512);
    // out = LN(PRE2)  fp32
    k_ln<false, true><<<4096, 256, 0, stream>>>(ws + OFF_X1, ln2g, ln2b, nullptr, out);
}

// Round 2
// 331.116 us; speedup vs baseline: 1.0472x; 1.0472x over previous
//
#include <hip/hip_runtime.h>

typedef _Float16 h16;
typedef _Float16 h16x8 __attribute__((ext_vector_type(8)));
typedef _Float16 h16x4 __attribute__((ext_vector_type(4)));
typedef _Float16 h16x2 __attribute__((ext_vector_type(2)));
typedef float f32x4 __attribute__((ext_vector_type(4)));

#define DEV static __device__ __forceinline__

// ---- workspace layout (h16 element offsets) ----
static constexpr size_t OFF_DATA = 0;          // 16384*256        data (f16)
static constexpr size_t OFF_W0T  = 4194304;    // 512*256          mlp_w0^T
static constexpr size_t OFF_W1T  = 4325376;    // 512*512          mlp_w1^T
static constexpr size_t OFF_W2PD = 4587520;    // 512*768          [mlp_w2 ; 2*pd_w]^T
static constexpr size_t OFF_QKVT = 4980736;    // 1536*512         [q|k|v]^T
static constexpr size_t OFF_OPIT = 5767168;    // 512*768          [o_w ; pi_w]^T
static constexpr size_t OFF_X1   = 6160384;    // 16384*512  X1 / KV-lo / PRE2
static constexpr size_t OFF_X2   = 14548992;   // 16384*512  X2 / KV-hi
static constexpr size_t OFF_KV   = OFF_X1;     // 16384*1024 (k|v per node)
static constexpr size_t OFF_P    = 22937600;   // 16384*512  P / LOCAL(in-place) / ATTN
// total: 31,326,208 elems = ~60 MB

DEV void gload16(const void* g, void* l)
{
    __builtin_amdgcn_global_load_lds(
        (__attribute__((address_space(1))) void*)(void*)g,
        (__attribute__((address_space(3))) void*)l, 16, 0, 0);
}

DEV float eluf(float x) { return x > 0.f ? x : __expf(x) - 1.f; }

// ---- data fp32 -> f16 ----
__global__ __launch_bounds__(256)
void k_cvt_data(const float* __restrict__ src, h16* __restrict__ dst)
{
    size_t i = ((size_t)blockIdx.x * 256 + threadIdx.x) * 4;
    float4 v = *(const float4*)(src + i);
    h16x4 o;
    o[0] = (h16)v.x; o[1] = (h16)v.y; o[2] = (h16)v.z; o[3] = (h16)v.w;
    *(h16x4*)(dst + i) = o;
}

// ---- all weight transposes (src [K][512] fp32 -> dst [n][k] f16, optional scale) ----
__global__ void k_prep_w(const float* __restrict__ w0, const float* __restrict__ w1,
                         const float* __restrict__ w2, const float* __restrict__ pdw,
                         const float* __restrict__ qw, const float* __restrict__ kw,
                         const float* __restrict__ vw, const float* __restrict__ ow,
                         const float* __restrict__ piw, h16* __restrict__ ws)
{
    int b = blockIdx.x;
    const float* src; h16* dst; int K, dstStride, dstKOff = 0, tb; float scale = 1.f;
    const int N = 512;
    if (b < 128)       { src = w0;  dst = ws + OFF_W0T;           K = 256; dstStride = 256; tb = 0; }
    else if (b < 384)  { src = w1;  dst = ws + OFF_W1T;           K = 512; dstStride = 512; tb = 128; }
    else if (b < 640)  { src = w2;  dst = ws + OFF_W2PD;          K = 512; dstStride = 768; tb = 384; }
    else if (b < 768)  { src = pdw; dst = ws + OFF_W2PD;          K = 256; dstStride = 768; dstKOff = 512; scale = 2.f; tb = 640; }
    else if (b < 1024) { src = qw;  dst = ws + OFF_QKVT;          K = 512; dstStride = 512; tb = 768; }
    else if (b < 1280) { src = kw;  dst = ws + OFF_QKVT + 262144; K = 512; dstStride = 512; tb = 1024; }
    else if (b < 1536) { src = vw;  dst = ws + OFF_QKVT + 524288; K = 512; dstStride = 512; tb = 1280; }
    else if (b < 1792) { src = ow;  dst = ws + OFF_OPIT;          K = 512; dstStride = 768; tb = 1536; }
    else               { src = piw; dst = ws + OFF_OPIT;          K = 256; dstStride = 768; dstKOff = 512; tb = 1792; }
    int t = b - tb;
    int tilesK = K >> 5;
    int tk = t % tilesK, tn = t / tilesK;
    __shared__ float tile[32][33];
    int tx = threadIdx.x, ty = threadIdx.y;
    #pragma unroll
    for (int r = 0; r < 32; r += 8)
        tile[ty + r][tx] = src[(size_t)(tk * 32 + ty + r) * N + tn * 32 + tx] * scale;
    __syncthreads();
    #pragma unroll
    for (int r = 0; r < 32; r += 8) {
        int n = tn * 32 + ty + r, k = tk * 32 + tx;
        dst[(size_t)n * dstStride + dstKOff + k] = (h16)tile[tx][ty + r];
    }
}

// ---- GEMM: C[M,N] = concat(A1[K1],A2[K2]) @ BT^T + bias ----
// 128x128 tile, 512 threads (8 waves as 2x4), each wave 64x32 -> 4x2 MFMA subtiles.
// BIASMODE: 0 = bias1[col]; 1 = bias1[col] + b2scale*bias2[col];
//           2 = segmented qkv bias + split output (out: cols 0..511 stride 512,
//               out2: cols 512..1535 stride 1024)
template<int BIASMODE, bool DOELU>
__global__ __launch_bounds__(512, 4)
void k_gemm(const h16* __restrict__ A1, const h16* __restrict__ A2,
            const int K1, const int K2,
            const h16* __restrict__ BT,
            const float* __restrict__ bias1, const float* __restrict__ bias2,
            const float* __restrict__ bias3, const float b2scale,
            h16* __restrict__ out, h16* __restrict__ out2, const int N)
{
    const int Kt = K1 + K2;
    __shared__ __align__(16) h16 sA[128 * 32];
    __shared__ __align__(16) h16 sB[128 * 32];
    const int tid  = threadIdx.x;
    const int lane = tid & 63;
    const int mBase = blockIdx.y * 128, nBase = blockIdx.x * 128;
    const int w  = tid >> 6;
    const int wm = (w >> 2) * 64;      // wave row base (0 or 64)
    const int wn = (w & 3) * 32;       // wave col base (0/32/64/96)
    const f32x4 zero = {0.f, 0.f, 0.f, 0.f};
    f32x4 acc[4][2];
    #pragma unroll
    for (int i = 0; i < 4; ++i) {
        #pragma unroll
        for (int j = 0; j < 2; ++j) acc[i][j] = zero;
    }

    const int ldR = tid >> 2;          // 0..127
    const int ldC = (tid & 3) * 8;     // k element offset
    const int lm = lane & 15, lk = (lane >> 4) * 8;

    for (int k0 = 0; k0 < Kt; k0 += 32) {
        const h16* Ab; int Ak, As;
        if (k0 < K1) { Ab = A1; Ak = k0;      As = K1; }
        else         { Ab = A2; Ak = k0 - K1; As = K2; }
        gload16(Ab + (size_t)(mBase + ldR) * As + Ak + ldC, &sA[ldR * 32 + ldC]);
        gload16(BT + (size_t)(nBase + ldR) * Kt + k0 + ldC, &sB[ldR * 32 + ldC]);
        __syncthreads();
        h16x8 af[4], bfr[2];
        #pragma unroll
        for (int i = 0; i < 4; ++i) af[i]  = *(const h16x8*)&sA[(wm + i * 16 + lm) * 32 + lk];
        #pragma unroll
        for (int j = 0; j < 2; ++j) bfr[j] = *(const h16x8*)&sB[(wn + j * 16 + lm) * 32 + lk];
        #pragma unroll
        for (int i = 0; i < 4; ++i) {
            #pragma unroll
            for (int j = 0; j < 2; ++j)
                acc[i][j] = __builtin_amdgcn_mfma_f32_16x16x32_f16(af[i], bfr[j], acc[i][j], 0, 0, 0);
        }
        __syncthreads();
    }

    const int lr4 = (lane >> 4) * 4;
    #pragma unroll
    for (int j = 0; j < 2; ++j) {
        const int col = nBase + wn + j * 16 + lm;
        float bv;
        if (BIASMODE == 0) bv = bias1[col];
        else if (BIASMODE == 1) bv = bias1[col] + b2scale * bias2[col];
        else {
            const int seg = col >> 9;
            const float* bp = seg == 0 ? bias1 : (seg == 1 ? bias2 : bias3);
            bv = bp[col & 511];
        }
        #pragma unroll
        for (int i = 0; i < 4; ++i) {
            const int row0 = mBase + wm + i * 16 + lr4;
            #pragma unroll
            for (int r = 0; r < 4; ++r) {
                float v = acc[i][j][r] + bv;
                if (DOELU) v = eluf(v);
                if (BIASMODE == 2) {
                    if (col < 512) out [(size_t)(row0 + r) * 512  + col]         = (h16)v;
                    else           out2[(size_t)(row0 + r) * 1024 + (col - 512)] = (h16)v;
                } else {
                    out[(size_t)(row0 + r) * N + col] = (h16)v;
                }
            }
        }
    }
}

// ---- layernorm (one wave per 512-row), optional ELU, optional fp32 out ----
template<bool DOELU, bool OUTF32>
__global__ __launch_bounds__(256)
void k_ln(const h16* __restrict__ X, const float* __restrict__ g, const float* __restrict__ b,
          h16* __restrict__ outH, float* __restrict__ outF)
{
    const int row  = blockIdx.x * 4 + (threadIdx.x >> 6);
    const int lane = threadIdx.x & 63;
    const h16x8 xv = *(const h16x8*)(X + (size_t)row * 512 + lane * 8);
    float v[8], s = 0.f, ss = 0.f;
    #pragma unroll
    for (int k = 0; k < 8; ++k) { v[k] = (float)xv[k]; s += v[k]; ss += v[k] * v[k]; }
    #pragma unroll
    for (int m = 1; m < 64; m <<= 1) { s += __shfl_xor(s, m, 64); ss += __shfl_xor(ss, m, 64); }
    const float mean = s * (1.f / 512.f);
    const float var  = ss * (1.f / 512.f) - mean * mean;
    const float rstd = rsqrtf(var + 1e-5f);
    #pragma unroll
    for (int k = 0; k < 8; ++k) {
        const int c = lane * 8 + k;
        float y = (v[k] - mean) * rstd * g[c] + b[c];
        if (DOELU) y = eluf(y);
        if (OUTF32) outF[(size_t)row * 512 + c] = y;
        else        outH[(size_t)row * 512 + c] = (h16)y;
    }
}

// ---- neighbor multi-head attention: one block per node, register-resident K/V ----
// wave 0: K rows j=0..7, wave 1: K rows j=8..15, wave 2: V j=0..7, wave 3: V j=8..15.
// Lane l owns columns l*8..l*8+7 (head = l>>3).
__global__ __launch_bounds__(256)
void k_attn(const h16* __restrict__ Q, const h16* __restrict__ KV,
            const int* __restrict__ nbr, h16* __restrict__ outA)
{
    const int n = blockIdx.x;
    const int tid = threadIdx.x, lane = tid & 63, wave = tid >> 6;
    __shared__ float sS[8][16];   // raw scores
    __shared__ float sW[8][16];   // softmax weights
    __shared__ __align__(16) float sP[2][512];  // V partial sums
    const int h = lane >> 3;
    const int cbase = lane * 8;
    const int isV = wave >> 1;
    const int jbase = (wave & 1) * 8;

    // gather: 8 rows of K or V, 16B per lane per row (wave-uniform neighbor idx -> s_load)
    h16x8 rows[8];
    #pragma unroll
    for (int r = 0; r < 8; ++r) {
        const int j = nbr[n * 16 + jbase + r];
        rows[r] = *(const h16x8*)&KV[(size_t)j * 1024 + (size_t)isV * 512 + cbase];
    }

    if (!isV) {
        const h16x8 qv = *(const h16x8*)&Q[(size_t)n * 512 + cbase];
        float part[8];
        #pragma unroll
        for (int r = 0; r < 8; ++r) {
            float s = 0.f;
            #pragma unroll
            for (int e = 0; e < 8; ++e) s += (float)qv[e] * (float)rows[r][e];
            part[r] = s;
        }
        // reduce across the 8 lanes of this head (lanes h*8 .. h*8+7)
        #pragma unroll
        for (int m = 1; m < 8; m <<= 1) {
            #pragma unroll
            for (int r = 0; r < 8; ++r) part[r] += __shfl_xor(part[r], m, 64);
        }
        if ((lane & 7) == 0) {
            #pragma unroll
            for (int r = 0; r < 8; ++r) sS[h][jbase + r] = part[r] * 0.125f;
        }
    }
    __syncthreads();

    // softmax over j per head: threads 0..127, (h = tid>>4, j = tid&15)
    if (tid < 128) {
        const int hh = tid >> 4, j = tid & 15;
        float s = sS[hh][j];
        float mx = s;
        #pragma unroll
        for (int m = 1; m < 16; m <<= 1) mx = fmaxf(mx, __shfl_xor(mx, m, 64));
        const float e = __expf(s - mx);
        float sum = e;
        #pragma unroll
        for (int m = 1; m < 16; m <<= 1) sum += __shfl_xor(sum, m, 64);
        sW[hh][j] = e / sum;
    }
    __syncthreads();

    if (isV) {
        float acc[8];
        #pragma unroll
        for (int e = 0; e < 8; ++e) acc[e] = 0.f;
        #pragma unroll
        for (int r = 0; r < 8; ++r) {
            const float wj = sW[h][jbase + r];
            #pragma unroll
            for (int e = 0; e < 8; ++e) acc[e] += wj * (float)rows[r][e];
        }
        float* dst = &sP[wave & 1][cbase];
        *(f32x4*)dst       = *(const f32x4*)&acc[0];
        *(f32x4*)(dst + 4) = *(const f32x4*)&acc[4];
    }
    __syncthreads();

    // combine halves and store (2 cols per thread, packed 32-bit store)
    const int c = tid * 2;
    const float v0 = sP[0][c] + sP[1][c];
    const float v1 = sP[0][c + 1] + sP[1][c + 1];
    h16x2 o; o[0] = (h16)v0; o[1] = (h16)v1;
    *(h16x2*)&outA[(size_t)n * 512 + c] = o;
}

extern "C" void kernel_launch(void* const* d_in, const int* in_sizes, int n_in,
                              void* d_out, int out_size, void* d_ws, size_t ws_size,
                              hipStream_t stream)
{
    const float* data = (const float*)d_in[0];
    const int*   nbr  = (const int*)d_in[1];
    const float* w0   = (const float*)d_in[2];
    const float* b0   = (const float*)d_in[3];
    const float* w1   = (const float*)d_in[4];
    const float* b1   = (const float*)d_in[5];
    const float* w2   = (const float*)d_in[6];
    const float* b2   = (const float*)d_in[7];
    const float* pdw  = (const float*)d_in[8];
    const float* pdb  = (const float*)d_in[9];
    const float* piw  = (const float*)d_in[10];
    const float* pib  = (const float*)d_in[11];
    const float* qw   = (const float*)d_in[12];
    const float* qb   = (const float*)d_in[13];
    const float* kw   = (const float*)d_in[14];
    const float* kb   = (const float*)d_in[15];
    const float* vw   = (const float*)d_in[16];
    const float* vb   = (const float*)d_in[17];
    const float* ow   = (const float*)d_in[18];
    const float* ob   = (const float*)d_in[19];
    const float* ln1g = (const float*)d_in[20];
    const float* ln1b = (const float*)d_in[21];
    const float* ln2g = (const float*)d_in[22];
    const float* ln2b = (const float*)d_in[23];
    h16*   ws  = (h16*)d_ws;
    float* out = (float*)d_out;
    h16*   qbuf = (h16*)d_out;   // Q parks in d_out until the attention kernel

    k_cvt_data<<<4096, 256, 0, stream>>>(data, ws + OFF_DATA);
    k_prep_w<<<1920, dim3(32, 8), 0, stream>>>(w0, w1, w2, pdw, qw, kw, vw, ow, piw, ws);

    dim3 gA(4, 128);   // N=512
    dim3 gQ(12, 128);  // N=1536
    // X1 = elu(data @ W0 + b0)
    k_gemm<0, true ><<<gA, 512, 0, stream>>>(ws + OFF_DATA, nullptr, 256, 0, ws + OFF_W0T,
                                             b0, nullptr, nullptr, 0.f,
                                             ws + OFF_X1, nullptr, 512);
    // X2 = elu(X1 @ W1 + b1)
    k_gemm<0, true ><<<gA, 512, 0, stream>>>(ws + OFF_X1, nullptr, 512, 0, ws + OFF_W1T,
                                             b1, nullptr, nullptr, 0.f,
                                             ws + OFF_X2, nullptr, 512);
    // P = X2 @ W2 + 2*(data @ pd_w) + (b2 + 2*pd_b)
    k_gemm<1, false><<<gA, 512, 0, stream>>>(ws + OFF_X2, ws + OFF_DATA, 512, 256, ws + OFF_W2PD,
                                             b2, pdb, nullptr, 2.f,
                                             ws + OFF_P, nullptr, 512);
    // LOCAL = elu(LN(P))  (in-place)
    k_ln<true, false><<<4096, 256, 0, stream>>>(ws + OFF_P, ln1g, ln1b, ws + OFF_P, nullptr);
    // Q(d_out) | KV(ws) = LOCAL @ [q|k|v] + bias
    k_gemm<2, false><<<gQ, 512, 0, stream>>>(ws + OFF_P, nullptr, 512, 0, ws + OFF_QKVT,
                                             qb, kb, vb, 0.f,
                                             qbuf, ws + OFF_KV, 1536);
    // ATTN (-> P region)
    k_attn<<<16384, 256, 0, stream>>>(qbuf, ws + OFF_KV, nbr, ws + OFF_P);
    // PRE2 = ATTN @ o_w + data @ pi_w + (o_b + pi_b)   (-> X1 region)
    k_gemm<1, false><<<gA, 512, 0, stream>>>(ws + OFF_P, ws + OFF_DATA, 512, 256, ws + OFF_OPIT,
                                             ob, pib, nullptr, 1.f,
                                             ws + OFF_X1, nullptr, 512);
    // out = LN(PRE2)  fp32
    k_ln<false, true><<<4096, 256, 0, stream>>>(ws + OFF_X1, ln2g, ln2b, nullptr, out);
}

// Round 3
// 323.290 us; speedup vs baseline: 1.0725x; 1.0242x over previous
//
#include <hip/hip_runtime.h>

typedef _Float16 h16;
typedef _Float16 h16x8 __attribute__((ext_vector_type(8)));
typedef _Float16 h16x4 __attribute__((ext_vector_type(4)));
typedef _Float16 h16x2 __attribute__((ext_vector_type(2)));
typedef float f32x4 __attribute__((ext_vector_type(4)));

#define DEV static __device__ __forceinline__

// ---- workspace layout (h16 element offsets) ----
static constexpr size_t OFF_DATA = 0;          // 16384*256        data (f16)
static constexpr size_t OFF_W0T  = 4194304;    // 512*256          mlp_w0^T
static constexpr size_t OFF_W1T  = 4325376;    // 512*512          mlp_w1^T
static constexpr size_t OFF_W2PD = 4587520;    // 512*768          [mlp_w2 ; 2*pd_w]^T
static constexpr size_t OFF_QKVT = 4980736;    // 1536*512         [q|k|v]^T
static constexpr size_t OFF_OPIT = 5767168;    // 512*768          [o_w ; pi_w]^T
static constexpr size_t OFF_X1   = 6160384;    // 16384*512  X1 / KV-lo / PRE2
static constexpr size_t OFF_X2   = 14548992;   // 16384*512  X2 / KV-hi
static constexpr size_t OFF_KV   = OFF_X1;     // 16384*1024 (k|v per node)
static constexpr size_t OFF_P    = 22937600;   // 16384*512  P / LOCAL(in-place) / ATTN
// total: 31,326,208 elems = ~60 MB

DEV void gload16(const void* g, void* l)
{
    __builtin_amdgcn_global_load_lds(
        (__attribute__((address_space(1))) void*)(void*)g,
        (__attribute__((address_space(3))) void*)l, 16, 0, 0);
}

DEV float eluf(float x) { return x > 0.f ? x : __expf(x) - 1.f; }

// ---- data fp32 -> f16 ----
__global__ __launch_bounds__(256)
void k_cvt_data(const float* __restrict__ src, h16* __restrict__ dst)
{
    size_t i = ((size_t)blockIdx.x * 256 + threadIdx.x) * 4;
    float4 v = *(const float4*)(src + i);
    h16x4 o;
    o[0] = (h16)v.x; o[1] = (h16)v.y; o[2] = (h16)v.z; o[3] = (h16)v.w;
    *(h16x4*)(dst + i) = o;
}

// ---- all weight transposes (src [K][512] fp32 -> dst [n][k] f16, optional scale) ----
__global__ void k_prep_w(const float* __restrict__ w0, const float* __restrict__ w1,
                         const float* __restrict__ w2, const float* __restrict__ pdw,
                         const float* __restrict__ qw, const float* __restrict__ kw,
                         const float* __restrict__ vw, const float* __restrict__ ow,
                         const float* __restrict__ piw, h16* __restrict__ ws)
{
    int b = blockIdx.x;
    const float* src; h16* dst; int K, dstStride, dstKOff = 0, tb; float scale = 1.f;
    const int N = 512;
    if (b < 128)       { src = w0;  dst = ws + OFF_W0T;           K = 256; dstStride = 256; tb = 0; }
    else if (b < 384)  { src = w1;  dst = ws + OFF_W1T;           K = 512; dstStride = 512; tb = 128; }
    else if (b < 640)  { src = w2;  dst = ws + OFF_W2PD;          K = 512; dstStride = 768; tb = 384; }
    else if (b < 768)  { src = pdw; dst = ws + OFF_W2PD;          K = 256; dstStride = 768; dstKOff = 512; scale = 2.f; tb = 640; }
    else if (b < 1024) { src = qw;  dst = ws + OFF_QKVT;          K = 512; dstStride = 512; tb = 768; }
    else if (b < 1280) { src = kw;  dst = ws + OFF_QKVT + 262144; K = 512; dstStride = 512; tb = 1024; }
    else if (b < 1536) { src = vw;  dst = ws + OFF_QKVT + 524288; K = 512; dstStride = 512; tb = 1280; }
    else if (b < 1792) { src = ow;  dst = ws + OFF_OPIT;          K = 512; dstStride = 768; tb = 1536; }
    else               { src = piw; dst = ws + OFF_OPIT;          K = 256; dstStride = 768; dstKOff = 512; tb = 1792; }
    int t = b - tb;
    int tilesK = K >> 5;
    int tk = t % tilesK, tn = t / tilesK;
    __shared__ float tile[32][33];
    int tx = threadIdx.x, ty = threadIdx.y;
    #pragma unroll
    for (int r = 0; r < 32; r += 8)
        tile[ty + r][tx] = src[(size_t)(tk * 32 + ty + r) * N + tn * 32 + tx] * scale;
    __syncthreads();
    #pragma unroll
    for (int r = 0; r < 32; r += 8) {
        int n = tn * 32 + ty + r, k = tk * 32 + tx;
        dst[(size_t)n * dstStride + dstKOff + k] = (h16)tile[tx][ty + r];
    }
}

// ---- GEMM: C[M,N] = concat(A1[K1],A2[K2]) @ BT^T + bias ----
// 128x128 tile, 512 threads (8 waves as 2x4), each wave 64x32 -> 4x2 MFMA subtiles.
// 1D grid of NT*128 blocks; swizzled so the NT n-blocks of one m-stripe share
// blockIdx%8 (same XCD under round-robin dispatch) -> A-tile reuse in that L2.
// BIASMODE: 0 = bias1[col]; 1 = bias1[col] + b2scale*bias2[col];
//           2 = segmented qkv bias + split output (out: cols 0..511 stride 512,
//               out2: cols 512..1535 stride 1024)
template<int BIASMODE, bool DOELU, int NT>
__global__ __launch_bounds__(512, 4)
void k_gemm(const h16* __restrict__ A1, const h16* __restrict__ A2,
            const int K1, const int K2,
            const h16* __restrict__ BT,
            const float* __restrict__ bias1, const float* __restrict__ bias2,
            const float* __restrict__ bias3, const float b2scale,
            h16* __restrict__ out, h16* __restrict__ out2, const int N)
{
    const int Kt = K1 + K2;
    __shared__ __align__(16) h16 sA[128 * 32];
    __shared__ __align__(16) h16 sB[128 * 32];
    const int tid  = threadIdx.x;
    const int lane = tid & 63;
    const int bswz = blockIdx.x;
    const int slot = bswz & 7;
    const int gg   = bswz >> 3;
    const int mBase = ((gg / NT) * 8 + slot) * 128;
    const int nBase = (gg % NT) * 128;
    const int w  = tid >> 6;
    const int wm = (w >> 2) * 64;      // wave row base (0 or 64)
    const int wn = (w & 3) * 32;       // wave col base (0/32/64/96)
    const f32x4 zero = {0.f, 0.f, 0.f, 0.f};
    f32x4 acc[4][2];
    #pragma unroll
    for (int i = 0; i < 4; ++i) {
        #pragma unroll
        for (int j = 0; j < 2; ++j) acc[i][j] = zero;
    }

    const int ldR = tid >> 2;          // 0..127
    const int ldC = (tid & 3) * 8;     // k element offset
    const int lm = lane & 15, lk = (lane >> 4) * 8;

    for (int k0 = 0; k0 < Kt; k0 += 32) {
        const h16* Ab; int Ak, As;
        if (k0 < K1) { Ab = A1; Ak = k0;      As = K1; }
        else         { Ab = A2; Ak = k0 - K1; As = K2; }
        gload16(Ab + (size_t)(mBase + ldR) * As + Ak + ldC, &sA[ldR * 32 + ldC]);
        gload16(BT + (size_t)(nBase + ldR) * Kt + k0 + ldC, &sB[ldR * 32 + ldC]);
        __syncthreads();
        h16x8 af[4], bfr[2];
        #pragma unroll
        for (int i = 0; i < 4; ++i) af[i]  = *(const h16x8*)&sA[(wm + i * 16 + lm) * 32 + lk];
        #pragma unroll
        for (int j = 0; j < 2; ++j) bfr[j] = *(const h16x8*)&sB[(wn + j * 16 + lm) * 32 + lk];
        #pragma unroll
        for (int i = 0; i < 4; ++i) {
            #pragma unroll
            for (int j = 0; j < 2; ++j)
                acc[i][j] = __builtin_amdgcn_mfma_f32_16x16x32_f16(af[i], bfr[j], acc[i][j], 0, 0, 0);
        }
        __syncthreads();
    }

    const int lr4 = (lane >> 4) * 4;
    #pragma unroll
    for (int j = 0; j < 2; ++j) {
        const int col = nBase + wn + j * 16 + lm;
        float bv;
        if (BIASMODE == 0) bv = bias1[col];
        else if (BIASMODE == 1) bv = bias1[col] + b2scale * bias2[col];
        else {
            const int seg = col >> 9;
            const float* bp = seg == 0 ? bias1 : (seg == 1 ? bias2 : bias3);
            bv = bp[col & 511];
        }
        #pragma unroll
        for (int i = 0; i < 4; ++i) {
            const int row0 = mBase + wm + i * 16 + lr4;
            #pragma unroll
            for (int r = 0; r < 4; ++r) {
                float v = acc[i][j][r] + bv;
                if (DOELU) v = eluf(v);
                if (BIASMODE == 2) {
                    if (col < 512) out [(size_t)(row0 + r) * 512  + col]         = (h16)v;
                    else           out2[(size_t)(row0 + r) * 1024 + (col - 512)] = (h16)v;
                } else {
                    out[(size_t)(row0 + r) * N + col] = (h16)v;
                }
            }
        }
    }
}

// ---- layernorm (one wave per 512-row), optional ELU, optional fp32 out ----
template<bool DOELU, bool OUTF32>
__global__ __launch_bounds__(256)
void k_ln(const h16* __restrict__ X, const float* __restrict__ g, const float* __restrict__ b,
          h16* __restrict__ outH, float* __restrict__ outF)
{
    const int row  = blockIdx.x * 4 + (threadIdx.x >> 6);
    const int lane = threadIdx.x & 63;
    const h16x8 xv = *(const h16x8*)(X + (size_t)row * 512 + lane * 8);
    float v[8], s = 0.f, ss = 0.f;
    #pragma unroll
    for (int k = 0; k < 8; ++k) { v[k] = (float)xv[k]; s += v[k]; ss += v[k] * v[k]; }
    #pragma unroll
    for (int m = 1; m < 64; m <<= 1) { s += __shfl_xor(s, m, 64); ss += __shfl_xor(ss, m, 64); }
    const float mean = s * (1.f / 512.f);
    const float var  = ss * (1.f / 512.f) - mean * mean;
    const float rstd = rsqrtf(var + 1e-5f);
    #pragma unroll
    for (int k = 0; k < 8; ++k) {
        const int c = lane * 8 + k;
        float y = (v[k] - mean) * rstd * g[c] + b[c];
        if (DOELU) y = eluf(y);
        if (OUTF32) outF[(size_t)row * 512 + c] = y;
        else        outH[(size_t)row * 512 + c] = (h16)y;
    }
}

// ---- neighbor multi-head attention: one block per 2 nodes, register-resident K/V ----
// Per node: wave 0: K rows j=0..7, wave 1: K rows j=8..15, wave 2: V j=0..7,
// wave 3: V j=8..15. Lane l owns columns l*8..l*8+7 (head = l>>3).
// Both nodes' gathers are issued up-front (16 outstanding 16B loads per thread).
__global__ __launch_bounds__(256)
void k_attn(const h16* __restrict__ Q, const h16* __restrict__ KV,
            const int* __restrict__ nbr, h16* __restrict__ outA)
{
    const int n0 = blockIdx.x * 2;
    const int tid = threadIdx.x, lane = tid & 63, wave = tid >> 6;
    __shared__ float sS[2][8][16];   // raw scores
    __shared__ float sW[2][8][16];   // softmax weights
    __shared__ __align__(16) float sP[2][2][512];  // V partial sums per node
    const int h = lane >> 3;
    const int cbase = lane * 8;
    const int isV = wave >> 1;
    const int jbase = (wave & 1) * 8;

    int idxA[8], idxB[8];
    #pragma unroll
    for (int r = 0; r < 8; ++r) idxA[r] = nbr[n0 * 16 + jbase + r];
    #pragma unroll
    for (int r = 0; r < 8; ++r) idxB[r] = nbr[(n0 + 1) * 16 + jbase + r];

    h16x8 rA[8], rB[8];
    #pragma unroll
    for (int r = 0; r < 8; ++r)
        rA[r] = *(const h16x8*)&KV[(size_t)idxA[r] * 1024 + (size_t)isV * 512 + cbase];
    #pragma unroll
    for (int r = 0; r < 8; ++r)
        rB[r] = *(const h16x8*)&KV[(size_t)idxB[r] * 1024 + (size_t)isV * 512 + cbase];

    if (!isV) {
        const h16x8 qA = *(const h16x8*)&Q[(size_t)n0 * 512 + cbase];
        const h16x8 qB = *(const h16x8*)&Q[(size_t)(n0 + 1) * 512 + cbase];
        float pA[8], pB[8];
        #pragma unroll
        for (int r = 0; r < 8; ++r) {
            float sa = 0.f, sb = 0.f;
            #pragma unroll
            for (int e = 0; e < 8; ++e) {
                sa += (float)qA[e] * (float)rA[r][e];
                sb += (float)qB[e] * (float)rB[r][e];
            }
            pA[r] = sa; pB[r] = sb;
        }
        #pragma unroll
        for (int m = 1; m < 8; m <<= 1) {
            #pragma unroll
            for (int r = 0; r < 8; ++r) {
                pA[r] += __shfl_xor(pA[r], m, 64);
                pB[r] += __shfl_xor(pB[r], m, 64);
            }
        }
        if ((lane & 7) == 0) {
            #pragma unroll
            for (int r = 0; r < 8; ++r) {
                sS[0][h][jbase + r] = pA[r] * 0.125f;
                sS[1][h][jbase + r] = pB[r] * 0.125f;
            }
        }
    }
    __syncthreads();

    // softmax: 256 threads = 2 nodes x 8 heads x 16 j
    {
        const int nn = tid >> 7, hh = (tid >> 4) & 7, j = tid & 15;
        float s = sS[nn][hh][j];
        float mx = s;
        #pragma unroll
        for (int m = 1; m < 16; m <<= 1) mx = fmaxf(mx, __shfl_xor(mx, m, 64));
        const float e = __expf(s - mx);
        float sum = e;
        #pragma unroll
        for (int m = 1; m < 16; m <<= 1) sum += __shfl_xor(sum, m, 64);
        sW[nn][hh][j] = e / sum;
    }
    __syncthreads();

    if (isV) {
        float accA[8], accB[8];
        #pragma unroll
        for (int e = 0; e < 8; ++e) { accA[e] = 0.f; accB[e] = 0.f; }
        #pragma unroll
        for (int r = 0; r < 8; ++r) {
            const float wa = sW[0][h][jbase + r];
            const float wb = sW[1][h][jbase + r];
            #pragma unroll
            for (int e = 0; e < 8; ++e) {
                accA[e] += wa * (float)rA[r][e];
                accB[e] += wb * (float)rB[r][e];
            }
        }
        float* dA = &sP[0][wave & 1][cbase];
        float* dB = &sP[1][wave & 1][cbase];
        *(f32x4*)dA       = *(const f32x4*)&accA[0];
        *(f32x4*)(dA + 4) = *(const f32x4*)&accA[4];
        *(f32x4*)dB       = *(const f32x4*)&accB[0];
        *(f32x4*)(dB + 4) = *(const f32x4*)&accB[4];
    }
    __syncthreads();

    // combine halves and store (2 cols per thread per node, packed 32-bit store)
    const int c = tid * 2;
    #pragma unroll
    for (int nn = 0; nn < 2; ++nn) {
        const float v0 = sP[nn][0][c] + sP[nn][1][c];
        const float v1 = sP[nn][0][c + 1] + sP[nn][1][c + 1];
        h16x2 o; o[0] = (h16)v0; o[1] = (h16)v1;
        *(h16x2*)&outA[(size_t)(n0 + nn) * 512 + c] = o;
    }
}

extern "C" void kernel_launch(void* const* d_in, const int* in_sizes, int n_in,
                              void* d_out, int out_size, void* d_ws, size_t ws_size,
                              hipStream_t stream)
{
    const float* data = (const float*)d_in[0];
    const int*   nbr  = (const int*)d_in[1];
    const float* w0   = (const float*)d_in[2];
    const float* b0   = (const float*)d_in[3];
    const float* w1   = (const float*)d_in[4];
    const float* b1   = (const float*)d_in[5];
    const float* w2   = (const float*)d_in[6];
    const float* b2   = (const float*)d_in[7];
    const float* pdw  = (const float*)d_in[8];
    const float* pdb  = (const float*)d_in[9];
    const float* piw  = (const float*)d_in[10];
    const float* pib  = (const float*)d_in[11];
    const float* qw   = (const float*)d_in[12];
    const float* qb   = (const float*)d_in[13];
    const float* kw   = (const float*)d_in[14];
    const float* kb   = (const float*)d_in[15];
    const float* vw   = (const float*)d_in[16];
    const float* vb   = (const float*)d_in[17];
    const float* ow   = (const float*)d_in[18];
    const float* ob   = (const float*)d_in[19];
    const float* ln1g = (const float*)d_in[20];
    const float* ln1b = (const float*)d_in[21];
    const float* ln2g = (const float*)d_in[22];
    const float* ln2b = (const float*)d_in[23];
    h16*   ws  = (h16*)d_ws;
    float* out = (float*)d_out;
    h16*   qbuf = (h16*)d_out;   // Q parks in d_out until the attention kernel

    k_cvt_data<<<4096, 256, 0, stream>>>(data, ws + OFF_DATA);
    k_prep_w<<<1920, dim3(32, 8), 0, stream>>>(w0, w1, w2, pdw, qw, kw, vw, ow, piw, ws);

    // X1 = elu(data @ W0 + b0)
    k_gemm<0, true , 4><<<512, 512, 0, stream>>>(ws + OFF_DATA, nullptr, 256, 0, ws + OFF_W0T,
                                             b0, nullptr, nullptr, 0.f,
                                             ws + OFF_X1, nullptr, 512);
    // X2 = elu(X1 @ W1 + b1)
    k_gemm<0, true , 4><<<512, 512, 0, stream>>>(ws + OFF_X1, nullptr, 512, 0, ws + OFF_W1T,
                                             b1, nullptr, nullptr, 0.f,
                                             ws + OFF_X2, nullptr, 512);
    // P = X2 @ W2 + 2*(data @ pd_w) + (b2 + 2*pd_b)
    k_gemm<1, false, 4><<<512, 512, 0, stream>>>(ws + OFF_X2, ws + OFF_DATA, 512, 256, ws + OFF_W2PD,
                                             b2, pdb, nullptr, 2.f,
                                             ws + OFF_P, nullptr, 512);
    // LOCAL = elu(LN(P))  (in-place)
    k_ln<true, false><<<4096, 256, 0, stream>>>(ws + OFF_P, ln1g, ln1b, ws + OFF_P, nullptr);
    // Q(d_out) | KV(ws) = LOCAL @ [q|k|v] + bias
    k_gemm<2, false, 12><<<1536, 512, 0, stream>>>(ws + OFF_P, nullptr, 512, 0, ws + OFF_QKVT,
                                             qb, kb, vb, 0.f,
                                             qbuf, ws + OFF_KV, 1536);
    // ATTN (-> P region)
    k_attn<<<8192, 256, 0, stream>>>(qbuf, ws + OFF_KV, nbr, ws + OFF_P);
    // PRE2 = ATTN @ o_w + data @ pi_w + (o_b + pi_b)   (-> X1 region)
    k_gemm<1, false, 4><<<512, 512, 0, stream>>>(ws + OFF_P, ws + OFF_DATA, 512, 256, ws + OFF_OPIT,
                                             ob, pib, nullptr, 1.f,
                                             ws + OFF_X1, nullptr, 512);
    // out = LN(PRE2)  fp32
    k_ln<false, true><<<4096, 256, 0, stream>>>(ws + OFF_X1, ln2g, ln2b, nullptr, out);
}

// Round 4
// 321.323 us; speedup vs baseline: 1.0791x; 1.0061x over previous
//
#include <hip/hip_runtime.h>

typedef _Float16 h16;
typedef _Float16 h16x8 __attribute__((ext_vector_type(8)));
typedef _Float16 h16x4 __attribute__((ext_vector_type(4)));
typedef _Float16 h16x2 __attribute__((ext_vector_type(2)));
typedef float f32x4 __attribute__((ext_vector_type(4)));

#define DEV static __device__ __forceinline__

// ---- workspace layout (h16 element offsets) ----
static constexpr size_t OFF_DATA = 0;          // 16384*256        data (f16)
static constexpr size_t OFF_W0T  = 4194304;    // 512*256          mlp_w0^T
static constexpr size_t OFF_W1T  = 4325376;    // 512*512          mlp_w1^T
static constexpr size_t OFF_W2PD = 4587520;    // 512*768          [mlp_w2 ; 2*pd_w]^T
static constexpr size_t OFF_QKVT = 4980736;    // 1536*512         [q|k|v]^T
static constexpr size_t OFF_OPIT = 5767168;    // 512*768          [o_w ; pi_w]^T
static constexpr size_t OFF_X1   = 6160384;    // 16384*512  X1 / KV-lo / PRE2
static constexpr size_t OFF_X2   = 14548992;   // 16384*512  X2 / KV-hi
static constexpr size_t OFF_KV   = OFF_X1;     // 16384*1024 (k|v per node)
static constexpr size_t OFF_P    = 22937600;   // 16384*512  P / LOCAL(in-place) / ATTN
// total: 31,326,208 elems = ~60 MB

DEV void gload16(const void* g, void* l)
{
    __builtin_amdgcn_global_load_lds(
        (__attribute__((address_space(1))) void*)(void*)g,
        (__attribute__((address_space(3))) void*)l, 16, 0, 0);
}

DEV float eluf(float x) { return x > 0.f ? x : __expf(x) - 1.f; }

// ---- data fp32 -> f16 ----
__global__ __launch_bounds__(256)
void k_cvt_data(const float* __restrict__ src, h16* __restrict__ dst)
{
    size_t i = ((size_t)blockIdx.x * 256 + threadIdx.x) * 4;
    float4 v = *(const float4*)(src + i);
    h16x4 o;
    o[0] = (h16)v.x; o[1] = (h16)v.y; o[2] = (h16)v.z; o[3] = (h16)v.w;
    *(h16x4*)(dst + i) = o;
}

// ---- all weight transposes (src [K][512] fp32 -> dst [n][k] f16, optional scale) ----
__global__ void k_prep_w(const float* __restrict__ w0, const float* __restrict__ w1,
                         const float* __restrict__ w2, const float* __restrict__ pdw,
                         const float* __restrict__ qw, const float* __restrict__ kw,
                         const float* __restrict__ vw, const float* __restrict__ ow,
                         const float* __restrict__ piw, h16* __restrict__ ws)
{
    int b = blockIdx.x;
    const float* src; h16* dst; int K, dstStride, dstKOff = 0, tb; float scale = 1.f;
    const int N = 512;
    if (b < 128)       { src = w0;  dst = ws + OFF_W0T;           K = 256; dstStride = 256; tb = 0; }
    else if (b < 384)  { src = w1;  dst = ws + OFF_W1T;           K = 512; dstStride = 512; tb = 128; }
    else if (b < 640)  { src = w2;  dst = ws + OFF_W2PD;          K = 512; dstStride = 768; tb = 384; }
    else if (b < 768)  { src = pdw; dst = ws + OFF_W2PD;          K = 256; dstStride = 768; dstKOff = 512; scale = 2.f; tb = 640; }
    else if (b < 1024) { src = qw;  dst = ws + OFF_QKVT;          K = 512; dstStride = 512; tb = 768; }
    else if (b < 1280) { src = kw;  dst = ws + OFF_QKVT + 262144; K = 512; dstStride = 512; tb = 1024; }
    else if (b < 1536) { src = vw;  dst = ws + OFF_QKVT + 524288; K = 512; dstStride = 512; tb = 1280; }
    else if (b < 1792) { src = ow;  dst = ws + OFF_OPIT;          K = 512; dstStride = 768; tb = 1536; }
    else               { src = piw; dst = ws + OFF_OPIT;          K = 256; dstStride = 768; dstKOff = 512; tb = 1792; }
    int t = b - tb;
    int tilesK = K >> 5;
    int tk = t % tilesK, tn = t / tilesK;
    __shared__ float tile[32][33];
    int tx = threadIdx.x, ty = threadIdx.y;
    #pragma unroll
    for (int r = 0; r < 32; r += 8)
        tile[ty + r][tx] = src[(size_t)(tk * 32 + ty + r) * N + tn * 32 + tx] * scale;
    __syncthreads();
    #pragma unroll
    for (int r = 0; r < 32; r += 8) {
        int n = tn * 32 + ty + r, k = tk * 32 + tx;
        dst[(size_t)n * dstStride + dstKOff + k] = (h16)tile[tx][ty + r];
    }
}

// ---- GEMM: C[M,N] = concat(A1[K1],A2[K2]) @ BT^T + bias ----
// 128x128 tile, 512 threads (8 waves as 2x4), each wave 64x32 -> 4x2 MFMA subtiles.
// 1D grid of NT*128 blocks; swizzled so the NT n-blocks of one m-stripe share
// blockIdx%8 (same XCD under round-robin dispatch) -> A-tile reuse in that L2.
// BIASMODE: 0 = bias1[col]; 1 = bias1[col] + b2scale*bias2[col];
//           2 = segmented qkv bias + split output (out: cols 0..511 stride 512,
//               out2: cols 512..1535 stride 1024)
template<int BIASMODE, bool DOELU, int NT>
__global__ __launch_bounds__(512, 4)
void k_gemm(const h16* __restrict__ A1, const h16* __restrict__ A2,
            const int K1, const int K2,
            const h16* __restrict__ BT,
            const float* __restrict__ bias1, const float* __restrict__ bias2,
            const float* __restrict__ bias3, const float b2scale,
            h16* __restrict__ out, h16* __restrict__ out2, const int N)
{
    const int Kt = K1 + K2;
    __shared__ __align__(16) h16 sA[128 * 32];
    __shared__ __align__(16) h16 sB[128 * 32];
    const int tid  = threadIdx.x;
    const int lane = tid & 63;
    const int bswz = blockIdx.x;
    const int slot = bswz & 7;
    const int gg   = bswz >> 3;
    const int mBase = ((gg / NT) * 8 + slot) * 128;
    const int nBase = (gg % NT) * 128;
    const int w  = tid >> 6;
    const int wm = (w >> 2) * 64;      // wave row base (0 or 64)
    const int wn = (w & 3) * 32;       // wave col base (0/32/64/96)
    const f32x4 zero = {0.f, 0.f, 0.f, 0.f};
    f32x4 acc[4][2];
    #pragma unroll
    for (int i = 0; i < 4; ++i) {
        #pragma unroll
        for (int j = 0; j < 2; ++j) acc[i][j] = zero;
    }

    const int ldR = tid >> 2;          // 0..127
    const int ldC = (tid & 3) * 8;     // k element offset
    const int lm = lane & 15, lk = (lane >> 4) * 8;

    for (int k0 = 0; k0 < Kt; k0 += 32) {
        const h16* Ab; int Ak, As;
        if (k0 < K1) { Ab = A1; Ak = k0;      As = K1; }
        else         { Ab = A2; Ak = k0 - K1; As = K2; }
        gload16(Ab + (size_t)(mBase + ldR) * As + Ak + ldC, &sA[ldR * 32 + ldC]);
        gload16(BT + (size_t)(nBase + ldR) * Kt + k0 + ldC, &sB[ldR * 32 + ldC]);
        __syncthreads();
        h16x8 af[4], bfr[2];
        #pragma unroll
        for (int i = 0; i < 4; ++i) af[i]  = *(const h16x8*)&sA[(wm + i * 16 + lm) * 32 + lk];
        #pragma unroll
        for (int j = 0; j < 2; ++j) bfr[j] = *(const h16x8*)&sB[(wn + j * 16 + lm) * 32 + lk];
        #pragma unroll
        for (int i = 0; i < 4; ++i) {
            #pragma unroll
            for (int j = 0; j < 2; ++j)
                acc[i][j] = __builtin_amdgcn_mfma_f32_16x16x32_f16(af[i], bfr[j], acc[i][j], 0, 0, 0);
        }
        __syncthreads();
    }

    const int lr4 = (lane >> 4) * 4;
    #pragma unroll
    for (int j = 0; j < 2; ++j) {
        const int col = nBase + wn + j * 16 + lm;
        float bv;
        if (BIASMODE == 0) bv = bias1[col];
        else if (BIASMODE == 1) bv = bias1[col] + b2scale * bias2[col];
        else {
            const int seg = col >> 9;
            const float* bp = seg == 0 ? bias1 : (seg == 1 ? bias2 : bias3);
            bv = bp[col & 511];
        }
        #pragma unroll
        for (int i = 0; i < 4; ++i) {
            const int row0 = mBase + wm + i * 16 + lr4;
            #pragma unroll
            for (int r = 0; r < 4; ++r) {
                float v = acc[i][j][r] + bv;
                if (DOELU) v = eluf(v);
                if (BIASMODE == 2) {
                    if (col < 512) out [(size_t)(row0 + r) * 512  + col]         = (h16)v;
                    else           out2[(size_t)(row0 + r) * 1024 + (col - 512)] = (h16)v;
                } else {
                    out[(size_t)(row0 + r) * N + col] = (h16)v;
                }
            }
        }
    }
}

// ---- layernorm (one wave per 512-row), optional ELU, optional fp32 out ----
template<bool DOELU, bool OUTF32>
__global__ __launch_bounds__(256)
void k_ln(const h16* __restrict__ X, const float* __restrict__ g, const float* __restrict__ b,
          h16* __restrict__ outH, float* __restrict__ outF)
{
    const int row  = blockIdx.x * 4 + (threadIdx.x >> 6);
    const int lane = threadIdx.x & 63;
    const h16x8 xv = *(const h16x8*)(X + (size_t)row * 512 + lane * 8);
    float v[8], s = 0.f, ss = 0.f;
    #pragma unroll
    for (int k = 0; k < 8; ++k) { v[k] = (float)xv[k]; s += v[k]; ss += v[k] * v[k]; }
    #pragma unroll
    for (int m = 1; m < 64; m <<= 1) { s += __shfl_xor(s, m, 64); ss += __shfl_xor(ss, m, 64); }
    const float mean = s * (1.f / 512.f);
    const float var  = ss * (1.f / 512.f) - mean * mean;
    const float rstd = rsqrtf(var + 1e-5f);
    #pragma unroll
    for (int k = 0; k < 8; ++k) {
        const int c = lane * 8 + k;
        float y = (v[k] - mean) * rstd * g[c] + b[c];
        if (DOELU) y = eluf(y);
        if (OUTF32) outF[(size_t)row * 512 + c] = y;
        else        outH[(size_t)row * 512 + c] = (h16)y;
    }
}

// ---- neighbor multi-head attention: ONE WAVE PER NODE, no LDS, no barriers ----
// Lane l owns columns l*8..l*8+7 (head h = l>>3, sub = l&7). All 32 gather
// loads (16 K rows + 16 V rows) are issued up-front; neighbor indices are
// wave-uniform (SGPR bases). Score reduce = 3-step 8-lane xor shuffle, after
// which every lane holds all 16 scores of its head -> softmax in registers.
__global__ __launch_bounds__(64)
void k_attn(const h16* __restrict__ Q, const h16* __restrict__ KV,
            const int* __restrict__ nbr, h16* __restrict__ outA)
{
    const int n = blockIdx.x;
    const int lane = threadIdx.x;
    const int cbase = lane * 8;

    const h16x8 qv = *(const h16x8*)&Q[(size_t)n * 512 + cbase];

    h16x8 kr[16], vr[16];
    #pragma unroll
    for (int j = 0; j < 16; ++j) {
        const int idx = nbr[n * 16 + j];              // wave-uniform -> s_load
        const h16* base = &KV[(size_t)idx * 1024 + cbase];
        kr[j] = *(const h16x8*)base;
        vr[j] = *(const h16x8*)(base + 512);
    }

    float s[16];
    #pragma unroll
    for (int j = 0; j < 16; ++j) {
        float d = 0.f;
        #pragma unroll
        for (int e = 0; e < 8; ++e) d += (float)qv[e] * (float)kr[j][e];
        s[j] = d;
    }
    #pragma unroll
    for (int m = 1; m < 8; m <<= 1) {
        #pragma unroll
        for (int j = 0; j < 16; ++j) s[j] += __shfl_xor(s[j], m, 64);
    }
    // softmax over 16 scores, redundantly per lane (all lanes of a head agree)
    float mx = -1e30f;
    #pragma unroll
    for (int j = 0; j < 16; ++j) { s[j] *= 0.125f; mx = fmaxf(mx, s[j]); }
    float sum = 0.f;
    #pragma unroll
    for (int j = 0; j < 16; ++j) { s[j] = __expf(s[j] - mx); sum += s[j]; }
    const float rinv = 1.f / sum;

    float acc[8];
    #pragma unroll
    for (int e = 0; e < 8; ++e) acc[e] = 0.f;
    #pragma unroll
    for (int j = 0; j < 16; ++j) {
        const float w = s[j] * rinv;
        #pragma unroll
        for (int e = 0; e < 8; ++e) acc[e] += w * (float)vr[j][e];
    }
    h16x8 o;
    #pragma unroll
    for (int e = 0; e < 8; ++e) o[e] = (h16)acc[e];
    *(h16x8*)&outA[(size_t)n * 512 + cbase] = o;
}

extern "C" void kernel_launch(void* const* d_in, const int* in_sizes, int n_in,
                              void* d_out, int out_size, void* d_ws, size_t ws_size,
                              hipStream_t stream)
{
    const float* data = (const float*)d_in[0];
    const int*   nbr  = (const int*)d_in[1];
    const float* w0   = (const float*)d_in[2];
    const float* b0   = (const float*)d_in[3];
    const float* w1   = (const float*)d_in[4];
    const float* b1   = (const float*)d_in[5];
    const float* w2   = (const float*)d_in[6];
    const float* b2   = (const float*)d_in[7];
    const float* pdw  = (const float*)d_in[8];
    const float* pdb  = (const float*)d_in[9];
    const float* piw  = (const float*)d_in[10];
    const float* pib  = (const float*)d_in[11];
    const float* qw   = (const float*)d_in[12];
    const float* qb   = (const float*)d_in[13];
    const float* kw   = (const float*)d_in[14];
    const float* kb   = (const float*)d_in[15];
    const float* vw   = (const float*)d_in[16];
    const float* vb   = (const float*)d_in[17];
    const float* ow   = (const float*)d_in[18];
    const float* ob   = (const float*)d_in[19];
    const float* ln1g = (const float*)d_in[20];
    const float* ln1b = (const float*)d_in[21];
    const float* ln2g = (const float*)d_in[22];
    const float* ln2b = (const float*)d_in[23];
    h16*   ws  = (h16*)d_ws;
    float* out = (float*)d_out;
    h16*   qbuf = (h16*)d_out;   // Q parks in d_out until the attention kernel

    k_cvt_data<<<4096, 256, 0, stream>>>(data, ws + OFF_DATA);
    k_prep_w<<<1920, dim3(32, 8), 0, stream>>>(w0, w1, w2, pdw, qw, kw, vw, ow, piw, ws);

    // X1 = elu(data @ W0 + b0)
    k_gemm<0, true , 4><<<512, 512, 0, stream>>>(ws + OFF_DATA, nullptr, 256, 0, ws + OFF_W0T,
                                             b0, nullptr, nullptr, 0.f,
                                             ws + OFF_X1, nullptr, 512);
    // X2 = elu(X1 @ W1 + b1)
    k_gemm<0, true , 4><<<512, 512, 0, stream>>>(ws + OFF_X1, nullptr, 512, 0, ws + OFF_W1T,
                                             b1, nullptr, nullptr, 0.f,
                                             ws + OFF_X2, nullptr, 512);
    // P = X2 @ W2 + 2*(data @ pd_w) + (b2 + 2*pd_b)
    k_gemm<1, false, 4><<<512, 512, 0, stream>>>(ws + OFF_X2, ws + OFF_DATA, 512, 256, ws + OFF_W2PD,
                                             b2, pdb, nullptr, 2.f,
                                             ws + OFF_P, nullptr, 512);
    // LOCAL = elu(LN(P))  (in-place)
    k_ln<true, false><<<4096, 256, 0, stream>>>(ws + OFF_P, ln1g, ln1b, ws + OFF_P, nullptr);
    // Q(d_out) | KV(ws) = LOCAL @ [q|k|v] + bias
    k_gemm<2, false, 12><<<1536, 512, 0, stream>>>(ws + OFF_P, nullptr, 512, 0, ws + OFF_QKVT,
                                             qb, kb, vb, 0.f,
                                             qbuf, ws + OFF_KV, 1536);
    // ATTN (-> P region)
    k_attn<<<16384, 64, 0, stream>>>(qbuf, ws + OFF_KV, nbr, ws + OFF_P);
    // PRE2 = ATTN @ o_w + data @ pi_w + (o_b + pi_b)   (-> X1 region)
    k_gemm<1, false, 4><<<512, 512, 0, stream>>>(ws + OFF_P, ws + OFF_DATA, 512, 256, ws + OFF_OPIT,
                                             ob, pib, nullptr, 1.f,
                                             ws + OFF_X1, nullptr, 512);
    // out = LN(PRE2)  fp32
    k_ln<false, true><<<4096, 256, 0, stream>>>(ws + OFF_X1, ln2g, ln2b, nullptr, out);
}